// Round 16
// baseline (252.213 us; speedup 1.0000x reference)
//
#include <hip/hip_runtime.h>
#include <math.h>
#include <float.h>
#include <stdint.h>

#define NN 1024
#define DD 128
#define HH 8
#define HDIM 16
#define KTOP 16
#define SCP 1032            // padded j-stride for h-major sc

typedef float vf4 __attribute__((ext_vector_type(4)));

__device__ __forceinline__ float wred_sum(float v) {
#pragma unroll
  for (int off = 32; off > 0; off >>= 1) v += __shfl_xor(v, off, 64);
  return v;
}

// non-temporal float4 load: streams from HBM without cache fill (e: zero reuse)
__device__ __forceinline__ float4 ntload4(const float* p) {
  vf4 r = __builtin_nontemporal_load((const vf4*)p);
  return make_float4(r.x, r.y, r.z, r.w);
}

// DPP lane-reduce add (VALU pipe, no LDS): v += v[partner]
template <int CTRL>
__device__ __forceinline__ float dpp_add(float v) {
  int x = __builtin_amdgcn_update_dpp(0, __float_as_int(v), CTRL, 0xF, 0xF, true);
  return v + __int_as_float(x);
}
#define DPP_XOR1 0xB1   // quad_perm(1,0,3,2)
#define DPP_XOR2 0x4E   // quad_perm(2,3,0,1)
#define DPP_ROR4 0x124  // row_ror:4 (16-lane row)
#define DPP_ROR8 0x128  // row_ror:8

// ---------------- K1: q,k,v = h @ W{q,k,v} + b ----------------
__global__ __launch_bounds__(128) void k_qkv(
    const float* __restrict__ h,
    const float* __restrict__ Wq, const float* __restrict__ bq,
    const float* __restrict__ Wk, const float* __restrict__ bk,
    const float* __restrict__ Wv, const float* __restrict__ bv,
    float* __restrict__ q, float* __restrict__ k, float* __restrict__ v) {
  __shared__ float hrow[4][DD];
  const int t = threadIdx.x;
  const int i0 = blockIdx.x * 4;
#pragma unroll
  for (int r = 0; r < 4; ++r) hrow[r][t] = h[(i0 + r) * DD + t];
  __syncthreads();
  const float* W[3] = {Wq, Wk, Wv};
  const float* B[3] = {bq, bk, bv};
  float* O[3] = {q, k, v};
#pragma unroll
  for (int m = 0; m < 3; ++m) {
    float a0 = 0.f, a1 = 0.f, a2 = 0.f, a3 = 0.f;
    const float* Wm = W[m];
#pragma unroll 8
    for (int c = 0; c < DD; ++c) {
      float w = Wm[c * DD + t];
      a0 += hrow[0][c] * w; a1 += hrow[1][c] * w;
      a2 += hrow[2][c] * w; a3 += hrow[3][c] * w;
    }
    float b = B[m][t];
    float* Om = O[m];
    Om[(i0 + 0) * DD + t] = a0 + b;
    Om[(i0 + 1) * DD + t] = a1 + b;
    Om[(i0 + 2) * DD + t] = a2 + b;
    Om[(i0 + 3) * DD + t] = a3 + b;
  }
}

// ---------------- K1b: scG[i][h][j] = be[h] + 0.25*q[i,h,:].k[j,h,:] ----------------
// Register-blocked GEMM per head (k-reuse via LDS -> k read 16x, not 1024x).
__global__ __launch_bounds__(256) void k_qk(
    const float* __restrict__ q, const float* __restrict__ kk,
    const float* __restrict__ be, float* __restrict__ scG) {
  __shared__ float qs[16 * 64];   // [d][i]
  __shared__ float ks[16 * 64];   // [d][j]
  const int t = threadIdx.x;
  const int i0 = blockIdx.x * 64;
  const int j0 = blockIdx.y * 64;
  const int h = blockIdx.z;
  {
    const int il = t >> 2;            // 0..63
    const int dq = (t & 3) * 4;       // 0,4,8,12
    float4 qv = *(const float4*)(q + (size_t)(i0 + il) * DD + h * HDIM + dq);
    qs[(dq + 0) * 64 + il] = qv.x * 0.25f;
    qs[(dq + 1) * 64 + il] = qv.y * 0.25f;
    qs[(dq + 2) * 64 + il] = qv.z * 0.25f;
    qs[(dq + 3) * 64 + il] = qv.w * 0.25f;
    float4 kv = *(const float4*)(kk + (size_t)(j0 + il) * DD + h * HDIM + dq);
    ks[(dq + 0) * 64 + il] = kv.x;
    ks[(dq + 1) * 64 + il] = kv.y;
    ks[(dq + 2) * 64 + il] = kv.z;
    ks[(dq + 3) * 64 + il] = kv.w;
  }
  __syncthreads();
  const int ti = t & 15;
  const int tj = t >> 4;
  float acc[4][4] = {{0,0,0,0},{0,0,0,0},{0,0,0,0},{0,0,0,0}};
#pragma unroll
  for (int d = 0; d < 16; ++d) {
    float4 qv = *(const float4*)&qs[d * 64 + ti * 4];
    float4 kv = *(const float4*)&ks[d * 64 + tj * 4];
    acc[0][0] += qv.x * kv.x; acc[0][1] += qv.x * kv.y; acc[0][2] += qv.x * kv.z; acc[0][3] += qv.x * kv.w;
    acc[1][0] += qv.y * kv.x; acc[1][1] += qv.y * kv.y; acc[1][2] += qv.y * kv.z; acc[1][3] += qv.y * kv.w;
    acc[2][0] += qv.z * kv.x; acc[2][1] += qv.z * kv.y; acc[2][2] += qv.z * kv.z; acc[2][3] += qv.z * kv.w;
    acc[3][0] += qv.w * kv.x; acc[3][1] += qv.w * kv.y; acc[3][2] += qv.w * kv.z; acc[3][3] += qv.w * kv.w;
  }
  const float beh = be[h];
#pragma unroll
  for (int a = 0; a < 4; ++a) {
    float4 st = make_float4(acc[a][0] + beh, acc[a][1] + beh,
                            acc[a][2] + beh, acc[a][3] + beh);
    *(float4*)(scG + (size_t)(i0 + ti * 4 + a) * (HH * NN) + h * NN + j0 + tj * 4) = st;
  }
}

// ---------------- K2: fused e-scores + top-k + softmax + PV ----------------
// Block (128 thr) per node i. sc preloaded from scG (qk+be). Loop: 32-row
// tiles, each lane owns 4 rows x 2 half-rows = 8 dense NT e-loads/iter —
// same issue structure that sustained 5.8 TB/s in R11, but ALL bytes are e.
__global__ __launch_bounds__(128, 2) void k_attn(
    const float* __restrict__ e, const float* __restrict__ We,
    const float* __restrict__ scG, const float* __restrict__ v,
    float* __restrict__ hattn) {
  __shared__ float sc[HH * SCP];       // 33 KB, h-major padded
  const int tid = threadIdx.x;
  const int lane = tid & 63;
  const int wv = tid >> 6;             // 0..1
  const int i = blockIdx.x;

  const int lrow = lane >> 4;          // 0..3
  const int c16 = lane & 15;
  const int cl0 = c16 * 4;             // lo cols cl0..+3 ; hi cols 64+cl0..+3
  const int r0 = wv * 8 + lrow;        // rows r0, r0+4, r0+16, r0+20 per tile

  const float* ebase = e + ((size_t)i << 17) + (size_t)r0 * DD + cl0;

#define ELOADSET(T, A0, A1, A2, A3, A4, A5, A6, A7)                \
  {                                                                \
    const float* xp_ = ebase + (size_t)(T) * (32 * DD);            \
    A0 = ntload4(xp_);            A1 = ntload4(xp_ + 64);          \
    A2 = ntload4(xp_ + 4 * DD);   A3 = ntload4(xp_ + 4 * DD + 64); \
    A4 = ntload4(xp_ + 16 * DD);  A5 = ntload4(xp_ + 16 * DD + 64);\
    A6 = ntload4(xp_ + 20 * DD);  A7 = ntload4(xp_ + 20 * DD + 64);\
  }

  // issue tile-0 loads first (latency hidden under weight/sc preload)
  float4 P0, P1, P2, P3, P4, P5, P6, P7;
  ELOADSET(0, P0, P1, P2, P3, P4, P5, P6, P7)

  // weights for the 8 owned cols -> 16 f4 regs
  float4 wlo[8], whi[8];
#pragma unroll
  for (int cl = 0; cl < 4; ++cl) {
    wlo[cl * 2]     = *(const float4*)(We + (cl0 + cl) * HH);
    wlo[cl * 2 + 1] = *(const float4*)(We + (cl0 + cl) * HH + 4);
    whi[cl * 2]     = *(const float4*)(We + (64 + cl0 + cl) * HH);
    whi[cl * 2 + 1] = *(const float4*)(We + (64 + cl0 + cl) * HH + 4);
  }

  // preload sc from scG (qk + bias), float4-coalesced
  {
    const float* scb = scG + (size_t)i * (HH * NN);
    for (int f = tid; f < 2048; f += 128) {
      int h = f >> 8, j4 = f & 255;
      *(float4*)&sc[h * SCP + j4 * 4] = *(const float4*)&scb[h * NN + j4 * 4];
    }
  }
  __syncthreads();

  for (int t = 0; t < 32; ++t) {       // 32 tiles x 32 rows
    float4 N0, N1, N2, N3, N4, N5, N6, N7;
    const bool more = (t + 1 < 32);
    if (more) ELOADSET(t + 1, N0, N1, N2, N3, N4, N5, N6, N7)

    float acc0[8] = {0,0,0,0,0,0,0,0};
    float acc1[8] = {0,0,0,0,0,0,0,0};
    float acc2[8] = {0,0,0,0,0,0,0,0};
    float acc3[8] = {0,0,0,0,0,0,0,0};
    const float eL0[4] = {P0.x, P0.y, P0.z, P0.w};
    const float eH0[4] = {P1.x, P1.y, P1.z, P1.w};
    const float eL1[4] = {P2.x, P2.y, P2.z, P2.w};
    const float eH1[4] = {P3.x, P3.y, P3.z, P3.w};
    const float eL2[4] = {P4.x, P4.y, P4.z, P4.w};
    const float eH2[4] = {P5.x, P5.y, P5.z, P5.w};
    const float eL3[4] = {P6.x, P6.y, P6.z, P6.w};
    const float eH3[4] = {P7.x, P7.y, P7.z, P7.w};
#pragma unroll
    for (int cl = 0; cl < 4; ++cl) {
      float4 wl0 = wlo[cl * 2], wl1 = wlo[cl * 2 + 1];
      float4 wh0 = whi[cl * 2], wh1 = whi[cl * 2 + 1];
#define ROWFMA(ACC, EL, EH)                                             \
      {                                                                 \
        float a_ = EL[cl], b_ = EH[cl];                                 \
        ACC[0] += a_ * wl0.x + b_ * wh0.x; ACC[1] += a_ * wl0.y + b_ * wh0.y; \
        ACC[2] += a_ * wl0.z + b_ * wh0.z; ACC[3] += a_ * wl0.w + b_ * wh0.w; \
        ACC[4] += a_ * wl1.x + b_ * wh1.x; ACC[5] += a_ * wl1.y + b_ * wh1.y; \
        ACC[6] += a_ * wl1.z + b_ * wh1.z; ACC[7] += a_ * wl1.w + b_ * wh1.w; \
      }
      ROWFMA(acc0, eL0, eH0)
      ROWFMA(acc1, eL1, eH1)
      ROWFMA(acc2, eL2, eH2)
      ROWFMA(acc3, eL3, eH3)
#undef ROWFMA
    }

    // 16-lane allreduce per row-acc (VALU pipe)
#pragma unroll
    for (int hh = 0; hh < 8; ++hh) {
      acc0[hh] = dpp_add<DPP_XOR1>(acc0[hh]);
      acc0[hh] = dpp_add<DPP_XOR2>(acc0[hh]);
      acc0[hh] = dpp_add<DPP_ROR4>(acc0[hh]);
      acc0[hh] = dpp_add<DPP_ROR8>(acc0[hh]);
      acc1[hh] = dpp_add<DPP_XOR1>(acc1[hh]);
      acc1[hh] = dpp_add<DPP_XOR2>(acc1[hh]);
      acc1[hh] = dpp_add<DPP_ROR4>(acc1[hh]);
      acc1[hh] = dpp_add<DPP_ROR8>(acc1[hh]);
      acc2[hh] = dpp_add<DPP_XOR1>(acc2[hh]);
      acc2[hh] = dpp_add<DPP_XOR2>(acc2[hh]);
      acc2[hh] = dpp_add<DPP_ROR4>(acc2[hh]);
      acc2[hh] = dpp_add<DPP_ROR8>(acc2[hh]);
      acc3[hh] = dpp_add<DPP_XOR1>(acc3[hh]);
      acc3[hh] = dpp_add<DPP_XOR2>(acc3[hh]);
      acc3[hh] = dpp_add<DPP_ROR4>(acc3[hh]);
      acc3[hh] = dpp_add<DPP_ROR8>(acc3[hh]);
    }

    const int jb = t * 32;
    const int sub = c16 & 3;
    if (sub == 0) {                    // writer for head h = c16>>2 (heads 0..3)
      const int h = c16 >> 2;
      float s0 = acc0[0], s1 = acc1[0], s2 = acc2[0], s3 = acc3[0];
#pragma unroll
      for (int hh = 1; hh < 4; ++hh)
        if (h == hh) { s0 = acc0[hh]; s1 = acc1[hh]; s2 = acc2[hh]; s3 = acc3[hh]; }
      sc[h * SCP + jb + r0]      += s0;
      sc[h * SCP + jb + r0 + 4]  += s1;
      sc[h * SCP + jb + r0 + 16] += s2;
      sc[h * SCP + jb + r0 + 20] += s3;
    } else if (sub == 1) {             // writer for head 4+(c16>>2) (heads 4..7)
      const int g = c16 >> 2;
      float s0 = acc0[4], s1 = acc1[4], s2 = acc2[4], s3 = acc3[4];
#pragma unroll
      for (int hh = 1; hh < 4; ++hh)
        if (g == hh) { s0 = acc0[4 + hh]; s1 = acc1[4 + hh]; s2 = acc2[4 + hh]; s3 = acc3[4 + hh]; }
      sc[(4 + g) * SCP + jb + r0]      += s0;
      sc[(4 + g) * SCP + jb + r0 + 4]  += s1;
      sc[(4 + g) * SCP + jb + r0 + 16] += s2;
      sc[(4 + g) * SCP + jb + r0 + 20] += s3;
    }

    if (more) {
      P0 = N0; P1 = N1; P2 = N2; P3 = N3;
      P4 = N4; P5 = N5; P6 = N6; P7 = N7;
    }
  }
#undef ELOADSET
  __syncthreads();

  // ---- phase 3: per head top-16 (lowest-j ties), softmax, PV ----
#pragma unroll 1
  for (int hp = 0; hp < 4; ++hp) {
    const int h = wv * 4 + hp;
    float val[16];
#pragma unroll
    for (int s = 0; s < 16; ++s) val[s] = sc[h * SCP + s * 64 + lane];
    int selj[16];
    float wgt[16];
    float vmax = 0.f, denom = 0.f;
#pragma unroll
    for (int t = 0; t < KTOP; ++t) {
      float bv = -FLT_MAX;
      int bj = 0x7FFFFFFF;
#pragma unroll
      for (int s = 0; s < 16; ++s) {
        float vs = val[s];
        int jj = s * 64 + lane;
        if (vs > bv) { bv = vs; bj = jj; }
      }
#pragma unroll
      for (int off = 32; off > 0; off >>= 1) {
        float ov = __shfl_xor(bv, off, 64);
        int oj = __shfl_xor(bj, off, 64);
        if (ov > bv || (ov == bv && oj < bj)) { bv = ov; bj = oj; }
      }
      selj[t] = bj;
      if (t == 0) vmax = bv;
      float wexp = expf(bv - vmax);
      wgt[t] = wexp;
      denom += wexp;
      const int so = bj >> 6;
      if ((bj & 63) == lane) {
#pragma unroll
        for (int s = 0; s < 16; ++s)
          if (s == so) val[s] = -FLT_MAX;
      }
    }
    const float inv = 1.0f / denom;
    const int d = lane & 15;
    float acc = 0.f;
#pragma unroll
    for (int t = 0; t < KTOP; ++t)
      acc += wgt[t] * v[(size_t)selj[t] * DD + h * HDIM + d];
    if (lane < 16) hattn[i * DD + h * HDIM + d] = acc * inv;
  }
}

// ---------------- K3: Wo proj + residual + LN1 + LSTMCell(zero state) ----------------
__global__ __launch_bounds__(128) void k_post1(
    const float* __restrict__ h, const float* __restrict__ hattn,
    const float* __restrict__ Wo, const float* __restrict__ bo,
    const float* __restrict__ Wih, const float* __restrict__ bih, const float* __restrict__ bhh,
    const float* __restrict__ ln1g, const float* __restrict__ ln1b,
    float* __restrict__ x2, float* __restrict__ outh, float* __restrict__ outc) {
  __shared__ float arow[4][DD];
  __shared__ __align__(16) float x1s[4][DD];
  __shared__ float redS[4][2], redQ[4][2];
  const int t = threadIdx.x;
  const int i0 = blockIdx.x * 4;
#pragma unroll
  for (int r = 0; r < 4; ++r) arow[r][t] = hattn[(i0 + r) * DD + t];
  __syncthreads();
  float o0 = 0.f, o1 = 0.f, o2 = 0.f, o3 = 0.f;
#pragma unroll 4
  for (int c = 0; c < DD; ++c) {
    float w = Wo[c * DD + t];
    o0 += arow[0][c] * w; o1 += arow[1][c] * w;
    o2 += arow[2][c] * w; o3 += arow[3][c] * w;
  }
  float ovals[4] = {o0, o1, o2, o3};
  const float bov = bo[t], g1 = ln1g[t], b1 = ln1b[t];
#pragma unroll
  for (int r = 0; r < 4; ++r) {
    float res = h[(i0 + r) * DD + t] + ovals[r] + bov;
    float s1 = wred_sum(res), s2 = wred_sum(res * res);
    if ((t & 63) == 0) { redS[r][t >> 6] = s1; redQ[r][t >> 6] = s2; }
    __syncthreads();
    float mu = (redS[r][0] + redS[r][1]) * (1.f / 128.f);
    float var = (redQ[r][0] + redQ[r][1]) * (1.f / 128.f) - mu * mu;
    x1s[r][t] = g1 * (res - mu) * rsqrtf(var + 1e-5f) + b1;
  }
  __syncthreads();
  float gi[4] = {0, 0, 0, 0}, gg[4] = {0, 0, 0, 0}, go[4] = {0, 0, 0, 0};
  const float* WI = Wih + (size_t)t * DD;
  const float* WG = Wih + (size_t)(t + 256) * DD;
  const float* WO = Wih + (size_t)(t + 384) * DD;
#pragma unroll 4
  for (int c4 = 0; c4 < 32; ++c4) {
    float4 wI = *(const float4*)(WI + c4 * 4);
    float4 wG = *(const float4*)(WG + c4 * 4);
    float4 wO = *(const float4*)(WO + c4 * 4);
#pragma unroll
    for (int r = 0; r < 4; ++r) {
      float4 xv = *(const float4*)&x1s[r][c4 * 4];
      gi[r] += xv.x * wI.x + xv.y * wI.y + xv.z * wI.z + xv.w * wI.w;
      gg[r] += xv.x * wG.x + xv.y * wG.y + xv.z * wG.z + xv.w * wG.w;
      go[r] += xv.x * wO.x + xv.y * wO.y + xv.z * wO.z + xv.w * wO.w;
    }
  }
  const float biI = bih[t] + bhh[t];
  const float biG = bih[t + 256] + bhh[t + 256];
  const float biO = bih[t + 384] + bhh[t + 384];
#pragma unroll
  for (int r = 0; r < 4; ++r) {
    float iv = 1.f / (1.f + expf(-(gi[r] + biI)));
    float gv = tanhf(gg[r] + biG);
    float ov = 1.f / (1.f + expf(-(go[r] + biO)));
    float cn = iv * gv;
    float hn = ov * tanhf(cn);
    outh[(i0 + r) * DD + t] = hn;
    outc[(i0 + r) * DD + t] = cn;
    x2[(i0 + r) * DD + t] = x1s[r][t] + hn;
  }
}

// ---------------- K4a: GraphNorm partial column sums ----------------
__global__ __launch_bounds__(256) void k_gncol(const float* __restrict__ x2,
                                               float* __restrict__ pS, float* __restrict__ pQ) {
  const int t = threadIdx.x, b = blockIdx.x;
  const int c = t & 127, half = t >> 7;
  const int r0 = b * 16 + half * 8;
  float s = 0.f, qq = 0.f;
#pragma unroll
  for (int r = 0; r < 8; ++r) {
    float v = x2[(r0 + r) * DD + c];
    s += v; qq += v * v;
  }
  pS[(b * 2 + half) * DD + c] = s;
  pQ[(b * 2 + half) * DD + c] = qq;
}

// ---------------- K4b: finalize stats ----------------
__global__ __launch_bounds__(128) void k_gnfin(const float* __restrict__ pS,
                                               const float* __restrict__ pQ,
                                               float* __restrict__ stats) {
  const int c = threadIdx.x;
  float s = 0.f, qq = 0.f;
#pragma unroll 8
  for (int kk = 0; kk < 128; ++kk) { s += pS[kk * DD + c]; qq += pQ[kk * DD + c]; }
  float mu = s * (1.f / 1024.f);
  float var = qq * (1.f / 1024.f) - mu * mu;
  stats[c] = mu;
  stats[DD + c] = rsqrtf(var + 1e-5f);
}

// ---------------- K5: GraphNorm apply + FFN + residual + LN2 ----------------
__global__ __launch_bounds__(256) void k_ffn(
    const float* __restrict__ x2, const float* __restrict__ stats,
    const float* __restrict__ gng, const float* __restrict__ gnb,
    const float* __restrict__ Wf1, const float* __restrict__ bf1,
    const float* __restrict__ Wf2, const float* __restrict__ bf2,
    const float* __restrict__ ln2g, const float* __restrict__ ln2b,
    float* __restrict__ out) {
  __shared__ float x3s[4][DD];
  __shared__ float hid[4][512];
  __shared__ float redC[4][256];
  __shared__ float redS[4][4], redQ[4][4];
  const int t = threadIdx.x;
  const int i0 = blockIdx.x * 4;
  for (int idx = t; idx < 4 * DD; idx += 256) {
    int r = idx >> 7, c = idx & 127;
    float vv = x2[(i0 + r) * DD + c];
    x3s[r][c] = gng[c] * (vv - stats[c]) * stats[DD + c] + gnb[c];
  }
  __syncthreads();
  {
    float a0[4] = {0, 0, 0, 0}, a1[4] = {0, 0, 0, 0};
#pragma unroll 2
    for (int c = 0; c < DD; ++c) {
      float w1 = Wf1[c * 512 + t];
      float w2 = Wf1[c * 512 + t + 256];
#pragma unroll
      for (int r = 0; r < 4; ++r) {
        float xv = x3s[r][c];
        a0[r] += xv * w1; a1[r] += xv * w2;
      }
    }
    float bb1 = bf1[t], bb2 = bf1[t + 256];
#pragma unroll
    for (int r = 0; r < 4; ++r) {
      hid[r][t] = fmaxf(a0[r] + bb1, 0.f);
      hid[r][t + 256] = fmaxf(a1[r] + bb2, 0.f);
    }
  }
  __syncthreads();
  const int d = t & 127, half = t >> 7;
  {
    float a[4] = {0, 0, 0, 0};
    for (int uu = 0; uu < 256; ++uu) {
      int u = half * 256 + uu;
      float w = Wf2[u * DD + d];
#pragma unroll
      for (int r = 0; r < 4; ++r) a[r] += hid[r][u] * w;
    }
#pragma unroll
    for (int r = 0; r < 4; ++r) redC[r][t] = a[r];
  }
  __syncthreads();
  const int lane = t & 63, wvv = t >> 6;
#pragma unroll 1
  for (int r = 0; r < 4; ++r) {
    float z = 0.f;
    if (t < DD) z = x3s[r][t] + redC[r][t] + redC[r][t + 128] + bf2[t];
    float s1 = wred_sum(z), s2 = wred_sum(z * z);
    if (lane == 0) { redS[r][wvv] = s1; redQ[r][wvv] = s2; }
    __syncthreads();
    float sum = redS[r][0] + redS[r][1] + redS[r][2] + redS[r][3];
    float sq = redQ[r][0] + redQ[r][1] + redQ[r][2] + redQ[r][3];
    float mu = sum * (1.f / 128.f);
    float var = sq * (1.f / 128.f) - mu * mu;
    float rs = rsqrtf(var + 1e-5f);
    if (t < DD) out[(i0 + r) * DD + t] = ln2g[t] * (z - mu) * rs + ln2b[t];
  }
}

extern "C" void kernel_launch(void* const* d_in, const int* in_sizes, int n_in,
                              void* d_out, int out_size, void* d_ws, size_t ws_size,
                              hipStream_t stream) {
  const float* h   = (const float*)d_in[0];
  const float* e   = (const float*)d_in[1];
  const float* Wq  = (const float*)d_in[3];
  const float* bq  = (const float*)d_in[4];
  const float* Wk  = (const float*)d_in[5];
  const float* bk  = (const float*)d_in[6];
  const float* Wv  = (const float*)d_in[7];
  const float* bv  = (const float*)d_in[8];
  const float* We  = (const float*)d_in[9];
  const float* be  = (const float*)d_in[10];
  const float* Wo  = (const float*)d_in[11];
  const float* bo  = (const float*)d_in[12];
  const float* Wf1 = (const float*)d_in[13];
  const float* bf1 = (const float*)d_in[14];
  const float* Wf2 = (const float*)d_in[15];
  const float* bf2 = (const float*)d_in[16];
  const float* Wih = (const float*)d_in[17];
  const float* bih = (const float*)d_in[19];
  const float* bhh = (const float*)d_in[20];
  const float* gng = (const float*)d_in[21];
  const float* gnb = (const float*)d_in[22];
  const float* l1g = (const float*)d_in[23];
  const float* l1b = (const float*)d_in[24];
  const float* l2g = (const float*)d_in[25];
  const float* l2b = (const float*)d_in[26];

  float* W = (float*)d_ws;
  float* q     = W;
  float* k     = W + 131072;
  float* v     = W + 262144;
  float* hattn = W + 393216;
  float* x2    = W + 524288;
  float* stats = W + 655360;
  float* pS    = W + 655616;
  float* pQ    = W + 672000;
  float* scG   = W + 1048576;   // 8M floats = 32 MB

  float* out  = (float*)d_out;
  float* outh = out + 131072;
  float* outc = out + 262144;

  hipLaunchKernelGGL(k_qkv, dim3(256), dim3(128), 0, stream,
                     h, Wq, bq, Wk, bk, Wv, bv, q, k, v);
  hipLaunchKernelGGL(k_qk, dim3(16, 16, 8), dim3(256), 0, stream,
                     q, k, be, scG);
  hipLaunchKernelGGL(k_attn, dim3(1024), dim3(128), 0, stream,
                     e, We, scG, v, hattn);
  hipLaunchKernelGGL(k_post1, dim3(256), dim3(128), 0, stream,
                     h, hattn, Wo, bo, Wih, bih, bhh, l1g, l1b, x2, outh, outc);
  hipLaunchKernelGGL(k_gncol, dim3(64), dim3(256), 0, stream, x2, pS, pQ);
  hipLaunchKernelGGL(k_gnfin, dim3(1), dim3(128), 0, stream, pS, pQ, stats);
  hipLaunchKernelGGL(k_ffn, dim3(256), dim3(256), 0, stream,
                     x2, stats, gng, gnb, Wf1, bf1, Wf2, bf2, l2g, l2b, out);
}

// Round 17
// 205.506 us; speedup vs baseline: 1.2273x; 1.2273x over previous
//
#include <hip/hip_runtime.h>
#include <math.h>
#include <float.h>
#include <stdint.h>

#define NN 1024
#define DD 128
#define HH 8
#define HDIM 16
#define KTOP 16
#define SCP 1032            // padded j-stride for h-major sc

typedef float vf4 __attribute__((ext_vector_type(4)));

__device__ __forceinline__ float wred_sum(float v) {
#pragma unroll
  for (int off = 32; off > 0; off >>= 1) v += __shfl_xor(v, off, 64);
  return v;
}

// non-temporal float4 load: streams from HBM without cache fill (e: zero reuse)
__device__ __forceinline__ float4 ntload4(const float* p) {
  vf4 r = __builtin_nontemporal_load((const vf4*)p);
  return make_float4(r.x, r.y, r.z, r.w);
}

// DPP lane-reduce add (VALU pipe, no LDS): v += v[partner]
template <int CTRL>
__device__ __forceinline__ float dpp_add(float v) {
  int x = __builtin_amdgcn_update_dpp(0, __float_as_int(v), CTRL, 0xF, 0xF, true);
  return v + __int_as_float(x);
}
#define DPP_XOR1 0xB1   // quad_perm(1,0,3,2)
#define DPP_XOR2 0x4E   // quad_perm(2,3,0,1)
#define DPP_ROR4 0x124  // row_ror:4 (16-lane row)
#define DPP_ROR8 0x128  // row_ror:8

// ---------------- K1: q,k,v = h @ W{q,k,v} + b ----------------
__global__ __launch_bounds__(128) void k_qkv(
    const float* __restrict__ h,
    const float* __restrict__ Wq, const float* __restrict__ bq,
    const float* __restrict__ Wk, const float* __restrict__ bk,
    const float* __restrict__ Wv, const float* __restrict__ bv,
    float* __restrict__ q, float* __restrict__ k, float* __restrict__ v) {
  __shared__ float hrow[4][DD];
  const int t = threadIdx.x;
  const int i0 = blockIdx.x * 4;
#pragma unroll
  for (int r = 0; r < 4; ++r) hrow[r][t] = h[(i0 + r) * DD + t];
  __syncthreads();
  const float* W[3] = {Wq, Wk, Wv};
  const float* B[3] = {bq, bk, bv};
  float* O[3] = {q, k, v};
#pragma unroll
  for (int m = 0; m < 3; ++m) {
    float a0 = 0.f, a1 = 0.f, a2 = 0.f, a3 = 0.f;
    const float* Wm = W[m];
#pragma unroll 8
    for (int c = 0; c < DD; ++c) {
      float w = Wm[c * DD + t];
      a0 += hrow[0][c] * w; a1 += hrow[1][c] * w;
      a2 += hrow[2][c] * w; a3 += hrow[3][c] * w;
    }
    float b = B[m][t];
    float* Om = O[m];
    Om[(i0 + 0) * DD + t] = a0 + b;
    Om[(i0 + 1) * DD + t] = a1 + b;
    Om[(i0 + 2) * DD + t] = a2 + b;
    Om[(i0 + 3) * DD + t] = a3 + b;
  }
}

// ---------------- K2: fused scores + top-k + softmax + PV (R11 winner) ----------------
// Block (128 thr) per node i. DENSE lane layout: each load instruction's 16
// lanes cover a contiguous 256-B half-row -> every DRAM granule touched once.
// e non-temporal; k inline (L2-hot, free BW + latency fill); DPP allreduce.
__global__ __launch_bounds__(128, 2) void k_attn(
    const float* __restrict__ e, const float* __restrict__ We, const float* __restrict__ be,
    const float* __restrict__ q, const float* __restrict__ kk, const float* __restrict__ v,
    float* __restrict__ hattn) {
  __shared__ float sc[HH * SCP];       // 33 KB, h-major padded
  const int tid = threadIdx.x;
  const int lane = tid & 63;
  const int wv = tid >> 6;             // 0..1
  const int i = blockIdx.x;

  const int lrow = lane >> 4;          // 0..3
  const int c16 = lane & 15;
  const int cl0 = c16 * 4;             // lo cols cl0..+3 ; hi cols 64+cl0..+3
  const int ra = wv * 8 + lrow;        // rows ra, ra+4 within a 16-row tile

  // weights for the 8 owned cols -> 16 f4 regs
  float4 wlo[8], whi[8];
#pragma unroll
  for (int cl = 0; cl < 4; ++cl) {
    wlo[cl * 2]     = *(const float4*)(We + (cl0 + cl) * HH);
    wlo[cl * 2 + 1] = *(const float4*)(We + (cl0 + cl) * HH + 4);
    whi[cl * 2]     = *(const float4*)(We + (64 + cl0 + cl) * HH);
    whi[cl * 2 + 1] = *(const float4*)(We + (64 + cl0 + cl) * HH + 4);
  }
  // q slices (pre-scaled by 1/sqrt(16))
  float4 qlo = *(const float4*)(q + (size_t)i * DD + cl0);
  float4 qhi = *(const float4*)(q + (size_t)i * DD + 64 + cl0);
  qlo.x *= 0.25f; qlo.y *= 0.25f; qlo.z *= 0.25f; qlo.w *= 0.25f;
  qhi.x *= 0.25f; qhi.y *= 0.25f; qhi.z *= 0.25f; qhi.w *= 0.25f;
  const float beh0 = be[c16 >> 2];       // head c16>>2   (lo writer)
  const float beh1 = be[4 + (c16 >> 2)]; // head 4+(c16>>2) (hi writer)

  const float* ei = e + ((size_t)i << 17);
  const float* paL = ei + (size_t)ra * DD + cl0;        // row a lo-half
  const float* pbL = paL + 4 * DD;                       // row b = ra+4
  const float* kaL = kk + (size_t)ra * DD + cl0;
  const float* kbL = kaL + 4 * DD;

  // prologue: iter-0 loads (e non-temporal, k cached) — all dense-contiguous
  float4 eaL = ntload4(paL), eaH = ntload4(paL + 64);
  float4 ebL = ntload4(pbL), ebH = ntload4(pbL + 64);
  float4 KaL = *(const float4*)(kaL), KaH = *(const float4*)(kaL + 64);
  float4 KbL = *(const float4*)(kbL), KbH = *(const float4*)(kbL + 64);

  for (int t = 0; t < 64; ++t) {       // 64 tiles x 16 rows
    float4 naL, naH, nbL, nbH, nKaL, nKaH, nKbL, nKbH;
    const bool more = (t + 1 < 64);
    if (more) {                        // depth-1 prefetch of tile t+1
      const float* xa = paL + (size_t)(t + 1) * (16 * DD);
      const float* xb = xa + 4 * DD;
      const float* ya = kaL + (size_t)(t + 1) * (16 * DD);
      const float* yb = ya + 4 * DD;
      naL = ntload4(xa);  naH = ntload4(xa + 64);
      nbL = ntload4(xb);  nbH = ntload4(xb + 64);
      nKaL = *(const float4*)(ya); nKaH = *(const float4*)(ya + 64);
      nKbL = *(const float4*)(yb); nKbH = *(const float4*)(yb + 64);
    }

    float acca[8] = {0,0,0,0,0,0,0,0};
    float accb[8] = {0,0,0,0,0,0,0,0};
    const float eLa[4] = {eaL.x, eaL.y, eaL.z, eaL.w};
    const float eHa[4] = {eaH.x, eaH.y, eaH.z, eaH.w};
    const float eLb[4] = {ebL.x, ebL.y, ebL.z, ebL.w};
    const float eHb[4] = {ebH.x, ebH.y, ebH.z, ebH.w};
#pragma unroll
    for (int cl = 0; cl < 4; ++cl) {
      float4 wl0 = wlo[cl * 2], wl1 = wlo[cl * 2 + 1];
      float4 wh0 = whi[cl * 2], wh1 = whi[cl * 2 + 1];
      float al = eLa[cl], ah = eHa[cl], bl = eLb[cl], bh = eHb[cl];
      acca[0] += al * wl0.x + ah * wh0.x; acca[1] += al * wl0.y + ah * wh0.y;
      acca[2] += al * wl0.z + ah * wh0.z; acca[3] += al * wl0.w + ah * wh0.w;
      acca[4] += al * wl1.x + ah * wh1.x; acca[5] += al * wl1.y + ah * wh1.y;
      acca[6] += al * wl1.z + ah * wh1.z; acca[7] += al * wl1.w + ah * wh1.w;
      accb[0] += bl * wl0.x + bh * wh0.x; accb[1] += bl * wl0.y + bh * wh0.y;
      accb[2] += bl * wl0.z + bh * wh0.z; accb[3] += bl * wl0.w + bh * wh0.w;
      accb[4] += bl * wl1.x + bh * wh1.x; accb[5] += bl * wl1.y + bh * wh1.y;
      accb[6] += bl * wl1.z + bh * wh1.z; accb[7] += bl * wl1.w + bh * wh1.w;
    }
    float qkaL = qlo.x*KaL.x + qlo.y*KaL.y + qlo.z*KaL.z + qlo.w*KaL.w;
    float qkaH = qhi.x*KaH.x + qhi.y*KaH.y + qhi.z*KaH.z + qhi.w*KaH.w;
    float qkbL = qlo.x*KbL.x + qlo.y*KbL.y + qlo.z*KbL.z + qlo.w*KbL.w;
    float qkbH = qhi.x*KbH.x + qhi.y*KbH.y + qhi.z*KbH.z + qhi.w*KbH.w;

    // e-acc: full 16-lane allreduce; qk: quad-reduce (head-aligned)
#pragma unroll
    for (int hh = 0; hh < 8; ++hh) {
      acca[hh] = dpp_add<DPP_XOR1>(acca[hh]);
      acca[hh] = dpp_add<DPP_XOR2>(acca[hh]);
      acca[hh] = dpp_add<DPP_ROR4>(acca[hh]);
      acca[hh] = dpp_add<DPP_ROR8>(acca[hh]);
      accb[hh] = dpp_add<DPP_XOR1>(accb[hh]);
      accb[hh] = dpp_add<DPP_XOR2>(accb[hh]);
      accb[hh] = dpp_add<DPP_ROR4>(accb[hh]);
      accb[hh] = dpp_add<DPP_ROR8>(accb[hh]);
    }
    qkaL = dpp_add<DPP_XOR2>(dpp_add<DPP_XOR1>(qkaL));
    qkaH = dpp_add<DPP_XOR2>(dpp_add<DPP_XOR1>(qkaH));
    qkbL = dpp_add<DPP_XOR2>(dpp_add<DPP_XOR1>(qkbL));
    qkbH = dpp_add<DPP_XOR2>(dpp_add<DPP_XOR1>(qkbH));

    const int j = t * 16 + ra;
    const int sub = c16 & 3;
    if (sub == 0) {                    // writer for head h = c16>>2 (lo)
      const int h = c16 >> 2;
      float sa = acca[0], sb = accb[0];
#pragma unroll
      for (int hh = 1; hh < 4; ++hh) if (h == hh) { sa = acca[hh]; sb = accb[hh]; }
      sc[h * SCP + j]     = sa + qkaL + beh0;
      sc[h * SCP + j + 4] = sb + qkbL + beh0;
    } else if (sub == 1) {             // writer for head 4 + (c16>>2) (hi)
      const int g = c16 >> 2;
      float sa = acca[4], sb = accb[4];
#pragma unroll
      for (int hh = 1; hh < 4; ++hh) if (g == hh) { sa = acca[4 + hh]; sb = accb[4 + hh]; }
      sc[(4 + g) * SCP + j]     = sa + qkaH + beh1;
      sc[(4 + g) * SCP + j + 4] = sb + qkbH + beh1;
    }

    if (more) {
      eaL = naL; eaH = naH; ebL = nbL; ebH = nbH;
      KaL = nKaL; KaH = nKaH; KbL = nKbL; KbH = nKbH;
    }
  }
  __syncthreads();

  // ---- phase 3: per head top-16 (lowest-j ties), softmax, PV ----
#pragma unroll 1
  for (int hp = 0; hp < 4; ++hp) {
    const int h = wv * 4 + hp;
    float val[16];
#pragma unroll
    for (int s = 0; s < 16; ++s) val[s] = sc[h * SCP + s * 64 + lane];
    int selj[16];
    float wgt[16];
    float vmax = 0.f, denom = 0.f;
#pragma unroll
    for (int t = 0; t < KTOP; ++t) {
      float bv = -FLT_MAX;
      int bj = 0x7FFFFFFF;
#pragma unroll
      for (int s = 0; s < 16; ++s) {
        float vs = val[s];
        int jj = s * 64 + lane;
        if (vs > bv) { bv = vs; bj = jj; }
      }
#pragma unroll
      for (int off = 32; off > 0; off >>= 1) {
        float ov = __shfl_xor(bv, off, 64);
        int oj = __shfl_xor(bj, off, 64);
        if (ov > bv || (ov == bv && oj < bj)) { bv = ov; bj = oj; }
      }
      selj[t] = bj;
      if (t == 0) vmax = bv;
      float wexp = expf(bv - vmax);
      wgt[t] = wexp;
      denom += wexp;
      const int so = bj >> 6;
      if ((bj & 63) == lane) {
#pragma unroll
        for (int s = 0; s < 16; ++s)
          if (s == so) val[s] = -FLT_MAX;
      }
    }
    const float inv = 1.0f / denom;
    const int d = lane & 15;
    float acc = 0.f;
#pragma unroll
    for (int t = 0; t < KTOP; ++t)
      acc += wgt[t] * v[(size_t)selj[t] * DD + h * HDIM + d];
    if (lane < 16) hattn[i * DD + h * HDIM + d] = acc * inv;
  }
}

// ---------------- K3: Wo proj + residual + LN1 + LSTMCell(zero state) ----------------
__global__ __launch_bounds__(128) void k_post1(
    const float* __restrict__ h, const float* __restrict__ hattn,
    const float* __restrict__ Wo, const float* __restrict__ bo,
    const float* __restrict__ Wih, const float* __restrict__ bih, const float* __restrict__ bhh,
    const float* __restrict__ ln1g, const float* __restrict__ ln1b,
    float* __restrict__ x2, float* __restrict__ outh, float* __restrict__ outc) {
  __shared__ float arow[4][DD];
  __shared__ __align__(16) float x1s[4][DD];
  __shared__ float redS[4][2], redQ[4][2];
  const int t = threadIdx.x;
  const int i0 = blockIdx.x * 4;
#pragma unroll
  for (int r = 0; r < 4; ++r) arow[r][t] = hattn[(i0 + r) * DD + t];
  __syncthreads();
  float o0 = 0.f, o1 = 0.f, o2 = 0.f, o3 = 0.f;
#pragma unroll 4
  for (int c = 0; c < DD; ++c) {
    float w = Wo[c * DD + t];
    o0 += arow[0][c] * w; o1 += arow[1][c] * w;
    o2 += arow[2][c] * w; o3 += arow[3][c] * w;
  }
  float ovals[4] = {o0, o1, o2, o3};
  const float bov = bo[t], g1 = ln1g[t], b1 = ln1b[t];
#pragma unroll
  for (int r = 0; r < 4; ++r) {
    float res = h[(i0 + r) * DD + t] + ovals[r] + bov;
    float s1 = wred_sum(res), s2 = wred_sum(res * res);
    if ((t & 63) == 0) { redS[r][t >> 6] = s1; redQ[r][t >> 6] = s2; }
    __syncthreads();
    float mu = (redS[r][0] + redS[r][1]) * (1.f / 128.f);
    float var = (redQ[r][0] + redQ[r][1]) * (1.f / 128.f) - mu * mu;
    x1s[r][t] = g1 * (res - mu) * rsqrtf(var + 1e-5f) + b1;
  }
  __syncthreads();
  float gi[4] = {0, 0, 0, 0}, gg[4] = {0, 0, 0, 0}, go[4] = {0, 0, 0, 0};
  const float* WI = Wih + (size_t)t * DD;
  const float* WG = Wih + (size_t)(t + 256) * DD;
  const float* WO = Wih + (size_t)(t + 384) * DD;
#pragma unroll 4
  for (int c4 = 0; c4 < 32; ++c4) {
    float4 wI = *(const float4*)(WI + c4 * 4);
    float4 wG = *(const float4*)(WG + c4 * 4);
    float4 wO = *(const float4*)(WO + c4 * 4);
#pragma unroll
    for (int r = 0; r < 4; ++r) {
      float4 xv = *(const float4*)&x1s[r][c4 * 4];
      gi[r] += xv.x * wI.x + xv.y * wI.y + xv.z * wI.z + xv.w * wI.w;
      gg[r] += xv.x * wG.x + xv.y * wG.y + xv.z * wG.z + xv.w * wG.w;
      go[r] += xv.x * wO.x + xv.y * wO.y + xv.z * wO.z + xv.w * wO.w;
    }
  }
  const float biI = bih[t] + bhh[t];
  const float biG = bih[t + 256] + bhh[t + 256];
  const float biO = bih[t + 384] + bhh[t + 384];
#pragma unroll
  for (int r = 0; r < 4; ++r) {
    float iv = 1.f / (1.f + expf(-(gi[r] + biI)));
    float gv = tanhf(gg[r] + biG);
    float ov = 1.f / (1.f + expf(-(go[r] + biO)));
    float cn = iv * gv;
    float hn = ov * tanhf(cn);
    outh[(i0 + r) * DD + t] = hn;
    outc[(i0 + r) * DD + t] = cn;
    x2[(i0 + r) * DD + t] = x1s[r][t] + hn;
  }
}

// ---------------- K4a: GraphNorm partial column sums ----------------
__global__ __launch_bounds__(256) void k_gncol(const float* __restrict__ x2,
                                               float* __restrict__ pS, float* __restrict__ pQ) {
  const int t = threadIdx.x, b = blockIdx.x;
  const int c = t & 127, half = t >> 7;
  const int r0 = b * 16 + half * 8;
  float s = 0.f, qq = 0.f;
#pragma unroll
  for (int r = 0; r < 8; ++r) {
    float v = x2[(r0 + r) * DD + c];
    s += v; qq += v * v;
  }
  pS[(b * 2 + half) * DD + c] = s;
  pQ[(b * 2 + half) * DD + c] = qq;
}

// ---------------- K4b: finalize stats ----------------
__global__ __launch_bounds__(128) void k_gnfin(const float* __restrict__ pS,
                                               const float* __restrict__ pQ,
                                               float* __restrict__ stats) {
  const int c = threadIdx.x;
  float s = 0.f, qq = 0.f;
#pragma unroll 8
  for (int kk = 0; kk < 128; ++kk) { s += pS[kk * DD + c]; qq += pQ[kk * DD + c]; }
  float mu = s * (1.f / 1024.f);
  float var = qq * (1.f / 1024.f) - mu * mu;
  stats[c] = mu;
  stats[DD + c] = rsqrtf(var + 1e-5f);
}

// ---------------- K5: GraphNorm apply + FFN + residual + LN2 ----------------
__global__ __launch_bounds__(256) void k_ffn(
    const float* __restrict__ x2, const float* __restrict__ stats,
    const float* __restrict__ gng, const float* __restrict__ gnb,
    const float* __restrict__ Wf1, const float* __restrict__ bf1,
    const float* __restrict__ Wf2, const float* __restrict__ bf2,
    const float* __restrict__ ln2g, const float* __restrict__ ln2b,
    float* __restrict__ out) {
  __shared__ float x3s[4][DD];
  __shared__ float hid[4][512];
  __shared__ float redC[4][256];
  __shared__ float redS[4][4], redQ[4][4];
  const int t = threadIdx.x;
  const int i0 = blockIdx.x * 4;
  for (int idx = t; idx < 4 * DD; idx += 256) {
    int r = idx >> 7, c = idx & 127;
    float vv = x2[(i0 + r) * DD + c];
    x3s[r][c] = gng[c] * (vv - stats[c]) * stats[DD + c] + gnb[c];
  }
  __syncthreads();
  {
    float a0[4] = {0, 0, 0, 0}, a1[4] = {0, 0, 0, 0};
#pragma unroll 2
    for (int c = 0; c < DD; ++c) {
      float w1 = Wf1[c * 512 + t];
      float w2 = Wf1[c * 512 + t + 256];
#pragma unroll
      for (int r = 0; r < 4; ++r) {
        float xv = x3s[r][c];
        a0[r] += xv * w1; a1[r] += xv * w2;
      }
    }
    float bb1 = bf1[t], bb2 = bf1[t + 256];
#pragma unroll
    for (int r = 0; r < 4; ++r) {
      hid[r][t] = fmaxf(a0[r] + bb1, 0.f);
      hid[r][t + 256] = fmaxf(a1[r] + bb2, 0.f);
    }
  }
  __syncthreads();
  const int d = t & 127, half = t >> 7;
  {
    float a[4] = {0, 0, 0, 0};
    for (int uu = 0; uu < 256; ++uu) {
      int u = half * 256 + uu;
      float w = Wf2[u * DD + d];
#pragma unroll
      for (int r = 0; r < 4; ++r) a[r] += hid[r][u] * w;
    }
#pragma unroll
    for (int r = 0; r < 4; ++r) redC[r][t] = a[r];
  }
  __syncthreads();
  const int lane = t & 63, wvv = t >> 6;
#pragma unroll 1
  for (int r = 0; r < 4; ++r) {
    float z = 0.f;
    if (t < DD) z = x3s[r][t] + redC[r][t] + redC[r][t + 128] + bf2[t];
    float s1 = wred_sum(z), s2 = wred_sum(z * z);
    if (lane == 0) { redS[r][wvv] = s1; redQ[r][wvv] = s2; }
    __syncthreads();
    float sum = redS[r][0] + redS[r][1] + redS[r][2] + redS[r][3];
    float sq = redQ[r][0] + redQ[r][1] + redQ[r][2] + redQ[r][3];
    float mu = sum * (1.f / 128.f);
    float var = sq * (1.f / 128.f) - mu * mu;
    float rs = rsqrtf(var + 1e-5f);
    if (t < DD) out[(i0 + r) * DD + t] = ln2g[t] * (z - mu) * rs + ln2b[t];
  }
}

extern "C" void kernel_launch(void* const* d_in, const int* in_sizes, int n_in,
                              void* d_out, int out_size, void* d_ws, size_t ws_size,
                              hipStream_t stream) {
  const float* h   = (const float*)d_in[0];
  const float* e   = (const float*)d_in[1];
  const float* Wq  = (const float*)d_in[3];
  const float* bq  = (const float*)d_in[4];
  const float* Wk  = (const float*)d_in[5];
  const float* bk  = (const float*)d_in[6];
  const float* Wv  = (const float*)d_in[7];
  const float* bv  = (const float*)d_in[8];
  const float* We  = (const float*)d_in[9];
  const float* be  = (const float*)d_in[10];
  const float* Wo  = (const float*)d_in[11];
  const float* bo  = (const float*)d_in[12];
  const float* Wf1 = (const float*)d_in[13];
  const float* bf1 = (const float*)d_in[14];
  const float* Wf2 = (const float*)d_in[15];
  const float* bf2 = (const float*)d_in[16];
  const float* Wih = (const float*)d_in[17];
  const float* bih = (const float*)d_in[19];
  const float* bhh = (const float*)d_in[20];
  const float* gng = (const float*)d_in[21];
  const float* gnb = (const float*)d_in[22];
  const float* l1g = (const float*)d_in[23];
  const float* l1b = (const float*)d_in[24];
  const float* l2g = (const float*)d_in[25];
  const float* l2b = (const float*)d_in[26];

  float* W = (float*)d_ws;
  float* q     = W;
  float* k     = W + 131072;
  float* v     = W + 262144;
  float* hattn = W + 393216;
  float* x2    = W + 524288;
  float* stats = W + 655360;
  float* pS    = W + 655616;
  float* pQ    = W + 672000;

  float* out  = (float*)d_out;
  float* outh = out + 131072;
  float* outc = out + 262144;

  hipLaunchKernelGGL(k_qkv, dim3(256), dim3(128), 0, stream,
                     h, Wq, bq, Wk, bk, Wv, bv, q, k, v);
  hipLaunchKernelGGL(k_attn, dim3(1024), dim3(128), 0, stream,
                     e, We, be, q, k, v, hattn);
  hipLaunchKernelGGL(k_post1, dim3(256), dim3(128), 0, stream,
                     h, hattn, Wo, bo, Wih, bih, bhh, l1g, l1b, x2, outh, outc);
  hipLaunchKernelGGL(k_gncol, dim3(64), dim3(256), 0, stream, x2, pS, pQ);
  hipLaunchKernelGGL(k_gnfin, dim3(1), dim3(128), 0, stream, pS, pQ, stats);
  hipLaunchKernelGGL(k_ffn, dim3(256), dim3(256), 0, stream,
                     x2, stats, gng, gnb, Wf1, bf1, Wf2, bf2, l2g, l2b, out);
}